// Round 2
// baseline (593.416 us; speedup 1.0000x reference)
//
#include <hip/hip_runtime.h>
#include <cstdint>

// Embedding gather + int4-group dequant:
//   out[t, d] = (q[x[t], d] - zero[x[t], d/128]) * scale[x[t], d/128]
// T = 16384 tokens, DIM = 1024, NGROUPS = 8 (group size 128).
//
// HARNESS NOTE: all integer inputs arrive widened to int32 ("integer ->
// const int*"), so qvals is [NUM_EMB,1024] int32 and zeros is [NUM_EMB,8]
// int32 — NOT int8. (Round-1 failure was casting these as int8.)
//
// One 256-thread block per token:
//   - lane loads 4 consecutive int32 qvals as one int4 (16 B coalesced)
//   - 4 elements never straddle a group boundary -> one (scale, zero)/lane
//   - x[blockIdx.x] is block-uniform -> scalar load

#define EMB_DIM 1024
#define EMB_NGROUPS 8

__global__ __launch_bounds__(256) void deq_embed_kernel(
    const int*   __restrict__ qvals,   // [NUM_EMB, 1024] int32 (int4 values)
    const float* __restrict__ scales,  // [NUM_EMB, 8] fp32
    const int*   __restrict__ zeros,   // [NUM_EMB, 8] int32
    const int*   __restrict__ x,       // [T] int32
    float*       __restrict__ out,     // [T, 1024] fp32
    int T)
{
    const int t = blockIdx.x;
    if (t >= T) return;

    const int tid = threadIdx.x;            // 0..255
    const long long row = x[t];             // block-uniform -> s_load

    const int e = tid << 2;                 // element offset within row, 0..1020
    const int g = tid >> 5;                 // group index = e / 128, 0..7

    const float s = scales[row * EMB_NGROUPS + g];
    const float z = (float)zeros[row * EMB_NGROUPS + g];

    // 4 int32 qvals in one aligned 16B load
    const int4 q = *reinterpret_cast<const int4*>(qvals + row * EMB_DIM + e);

    float4 o;
    o.x = ((float)q.x - z) * s;
    o.y = ((float)q.y - z) * s;
    o.z = ((float)q.z - z) * s;
    o.w = ((float)q.w - z) * s;

    *reinterpret_cast<float4*>(out + (size_t)t * EMB_DIM + e) = o;
}

extern "C" void kernel_launch(void* const* d_in, const int* in_sizes, int n_in,
                              void* d_out, int out_size, void* d_ws, size_t ws_size,
                              hipStream_t stream) {
    const int*   qvals  = (const int*)  d_in[0];
    const float* scales = (const float*)d_in[1];
    const int*   zeros  = (const int*)  d_in[2];
    const int*   x      = (const int*)  d_in[3];
    float*       out    = (float*)      d_out;

    const int T = in_sizes[3];              // 8 * 2048 = 16384 tokens

    deq_embed_kernel<<<dim3(T), dim3(256), 0, stream>>>(
        qvals, scales, zeros, x, out, T);
}